// Round 6
// baseline (521.876 us; speedup 1.0000x reference)
//
#include <hip/hip_runtime.h>

// Quadtree attention forward, 3 levels. B=4, C=128, nh=8, d=16, topks=(16,8,8).
// Round 6: coarse K/V staged through block LDS (4x traffic cut, was L2/L3-BW
// bound); q0/q1 token-major transposes (kill scattered q reads in mid/fine);
// coarse reads original layout (no level-2 transpose needed).

#define DEV static __device__ __forceinline__

DEV float wave_max(float v){
  #pragma unroll
  for(int o=32;o>0;o>>=1) v = fmaxf(v, __shfl_xor(v,o,64));
  return v;
}
DEV float wave_sum(float v){
  #pragma unroll
  for(int o=32;o>0;o>>=1) v += __shfl_xor(v,o,64);
  return v;
}
DEV float half_max(float v){
  #pragma unroll
  for(int o=16;o>0;o>>=1) v = fmaxf(v, __shfl_xor(v,o,64));
  return v;
}
DEV float half_sum(float v){
  #pragma unroll
  for(int o=16;o>0;o>>=1) v += __shfl_xor(v,o,64);
  return v;
}
DEV void wave_argmax(float& v, int& idx){
  #pragma unroll
  for(int o=32;o>0;o>>=1){
    float ov = __shfl_xor(v,o,64);
    int   oi = __shfl_xor(idx,o,64);
    if (ov > v || (ov == v && oi < idx)) { v = ov; idx = oi; }
  }
}

// lane owns sc[j] for s = (j>>2)*256 + lane*4 + (j&3); j ascending == s ascending.
DEV int s_of(int j, int lane){ return ((j>>2)<<8) + lane*4 + (j&3); }

// masked local top-4 scan (ascending j, strict > => tie keeps lowest s)
DEV void scan4(const float (&sc)[16], unsigned &rem, float (&tv)[4], int (&tc)[4]){
  #pragma unroll
  for(int t=0;t<4;t++){
    float bv=-1e30f; int bc=0;
    #pragma unroll
    for(int c=0;c<16;c++){
      const bool ok = (((rem>>c)&1u)==0u) && (sc[c] > bv);
      bv = ok ? sc[c] : bv;
      bc = ok ? c : bc;
    }
    tv[t]=bv; tc[t]=bc; rem |= (1u<<bc);
  }
}

// top-16 for two queries, interleaved rounds; ties -> lowest s.
DEV void top16_pair(const float (&sc0)[16], const float (&sc1)[16], int lane,
                    int &cap0, int &cap1){
  unsigned rem0=0u, rem1=0u;
  float tv0[4], tv1[4]; int tc0[4], tc1[4];
  scan4(sc0, rem0, tv0, tc0);
  scan4(sc1, rem1, tv1, tc1);
  cap0=0; cap1=0;
  #pragma unroll 1
  for(int r=0;r<16;r++){
    const float M0 = wave_max(tv0[0]);
    const float M1 = wave_max(tv1[0]);
    const unsigned long long k0 = __ballot(tv0[0]==M0);
    const unsigned long long k1 = __ballot(tv1[0]==M1);
    int wl0 = (int)__ffsll(k0)-1, ws0;
    int wl1 = (int)__ffsll(k1)-1, ws1;
    if (__popcll(k0)==1){ const int jw = __shfl(tc0[0], wl0); ws0 = s_of(jw, wl0); }
    else {
      int sel = (tv0[0]==M0) ? s_of(tc0[0], lane) : 0x7fffffff;
      #pragma unroll
      for(int o=32;o>0;o>>=1) sel = min(sel, __shfl_xor(sel,o,64));
      ws0 = sel; wl0 = (ws0>>2)&63;
    }
    if (__popcll(k1)==1){ const int jw = __shfl(tc1[0], wl1); ws1 = s_of(jw, wl1); }
    else {
      int sel = (tv1[0]==M1) ? s_of(tc1[0], lane) : 0x7fffffff;
      #pragma unroll
      for(int o=32;o>0;o>>=1) sel = min(sel, __shfl_xor(sel,o,64));
      ws1 = sel; wl1 = (ws1>>2)&63;
    }
    cap0 = (lane==r) ? ws0 : cap0;
    cap1 = (lane==r) ? ws1 : cap1;
    if (lane==wl0){
      const int jw = ((ws0>>8)<<2) | (ws0&3);
      tv0[0]=tv0[1]; tc0[0]=tc0[1];
      tv0[1]=tv0[2]; tc0[1]=tc0[2];
      tv0[2]=tv0[3]; tc0[2]=tc0[3];
      tv0[3]=-1e30f; tc0[3]=jw*0;
      if (tv0[0] < -1e29f) scan4(sc0, rem0, tv0, tc0);
    }
    if (lane==wl1){
      const int jw = ((ws1>>8)<<2) | (ws1&3);
      tv1[0]=tv1[1]; tc1[0]=tc1[1];
      tv1[1]=tv1[2]; tc1[1]=tc1[2];
      tv1[2]=tv1[3]; tc1[2]=tc1[3];
      tv1[3]=-1e30f; tc1[3]=jw*0;
      if (tv1[0] < -1e29f) scan4(sc1, rem1, tv1, tc1);
    }
  }
}

// -------- merged transpose: [bh][16][S] -> [bh*S][16] ----------------------
template<bool HASQ>
__global__ __launch_bounds__(256) void k_transpose_all(
    const float* __restrict__ k0, const float* __restrict__ v0, const float* __restrict__ q0,
    const float* __restrict__ k1, const float* __restrict__ v1, const float* __restrict__ q1,
    float* __restrict__ ktok0, float* __restrict__ vtok0, float* __restrict__ qtok0,
    float* __restrict__ ktok1, float* __restrict__ vtok1, float* __restrict__ qtok1)
{
  const int blk = blockIdx.x;
  const float* src; float* dst; int lgS, base;
  if (HASQ){
    if      (blk < 2048){ lgS=14; src=k0; dst=ktok0; base=0; }
    else if (blk < 4096){ lgS=14; src=v0; dst=vtok0; base=2048; }
    else if (blk < 6144){ lgS=14; src=q0; dst=qtok0; base=4096; }
    else if (blk < 6656){ lgS=12; src=k1; dst=ktok1; base=6144; }
    else if (blk < 7168){ lgS=12; src=v1; dst=vtok1; base=6656; }
    else                { lgS=12; src=q1; dst=qtok1; base=7168; }
  } else {
    if      (blk < 2048){ lgS=14; src=k0; dst=ktok0; base=0; }
    else if (blk < 4096){ lgS=14; src=v0; dst=vtok0; base=2048; }
    else if (blk < 4608){ lgS=12; src=k1; dst=ktok1; base=4096; }
    else                { lgS=12; src=v1; dst=vtok1; base=4608; }
  }
  const int id = (blk-base)*256 + threadIdx.x;
  const int s = id & ((1<<lgS)-1), bh = id >> lgS;
  const float* sp = src + ((size_t)bh<<(lgS+4)) + s;
  float r[16];
  #pragma unroll
  for(int dd=0;dd<16;dd++) r[dd] = sp[(size_t)dd<<lgS];
  float4* dp = (float4*)(dst + (size_t)id*16);
  dp[0] = make_float4(r[0],r[1],r[2],r[3]);
  dp[1] = make_float4(r[4],r[5],r[6],r[7]);
  dp[2] = make_float4(r[8],r[9],r[10],r[11]);
  dp[3] = make_float4(r[12],r[13],r[14],r[15]);
}

// ---------------- coarse: full attention over S=1024, top-16 ----------------
// 256 thr = 4 waves, 8 queries/block (2/wave), all same bh. K then V streamed
// through one 16KB LDS chunk (256 tokens), shared by all 8 queries.
__global__ __launch_bounds__(256) void k_coarse(
    const float* __restrict__ q, const float* __restrict__ k, const float* __restrict__ v,
    float* __restrict__ msg0, int* __restrict__ topk0)
{
  __shared__ float4 s_t[16*64];      // [dd][64 float4] = 16KB
  const int tid = threadIdx.x, wid = tid>>6, lane = tid&63;
  const int blk = blockIdx.x;
  const int bh  = blk>>7;                  // 128 blocks per bh
  const int l0  = (blk&127)*8 + wid*2;     // wave's first query (uniform)
  const int gq0 = bh*1024 + l0;

  const float* qb = q + (size_t)bh*16384;
  const float* kb = k + (size_t)bh*16384;
  const float* vb = v + (size_t)bh*16384;

  float qv0[16], qv1[16];
  #pragma unroll
  for(int dd=0;dd<16;dd++){ qv0[dd]=qb[dd*1024+l0]; qv1[dd]=qb[dd*1024+l0+1]; }

  // ---- pass 1: scores; lane owns s = ch*256 + lane*4 + e ----
  float sc0[16], sc1[16];
  #pragma unroll
  for(int j=0;j<16;j++){ sc0[j]=0.f; sc1[j]=0.f; }
  #pragma unroll
  for(int ch=0;ch<4;ch++){
    __syncthreads();
    #pragma unroll
    for(int i=0;i<4;i++){
      const int f = tid + i*256, dd = f>>6, g = f&63;
      s_t[f] = ((const float4*)(kb + dd*1024 + ch*256))[g];
    }
    __syncthreads();
    #pragma unroll
    for(int dd=0;dd<16;dd++){
      const float4 kf = s_t[dd*64 + lane];
      const float q0d = qv0[dd], q1d = qv1[dd];
      sc0[ch*4+0]=fmaf(q0d,kf.x,sc0[ch*4+0]); sc0[ch*4+1]=fmaf(q0d,kf.y,sc0[ch*4+1]);
      sc0[ch*4+2]=fmaf(q0d,kf.z,sc0[ch*4+2]); sc0[ch*4+3]=fmaf(q0d,kf.w,sc0[ch*4+3]);
      sc1[ch*4+0]=fmaf(q1d,kf.x,sc1[ch*4+0]); sc1[ch*4+1]=fmaf(q1d,kf.y,sc1[ch*4+1]);
      sc1[ch*4+2]=fmaf(q1d,kf.z,sc1[ch*4+2]); sc1[ch*4+3]=fmaf(q1d,kf.w,sc1[ch*4+3]);
    }
  }
  #pragma unroll
  for(int j=0;j<16;j++){ sc0[j]*=0.25f; sc1[j]*=0.25f; }

  // ---- top-16 on scores (exp monotone) ----
  int cap0, cap1;
  top16_pair(sc0, sc1, lane, cap0, cap1);
  if (lane < 16){
    topk0[(size_t)gq0*16 + lane]     = cap0;
    topk0[(size_t)(gq0+1)*16 + lane] = cap1;
  }

  // ---- softmax in place ----
  float m0=-1e30f, m1=-1e30f;
  #pragma unroll
  for(int j=0;j<16;j++){ m0=fmaxf(m0,sc0[j]); m1=fmaxf(m1,sc1[j]); }
  m0 = wave_max(m0); m1 = wave_max(m1);
  float s0=0.f, s1=0.f;
  #pragma unroll
  for(int j=0;j<16;j++){ sc0[j]=__expf(sc0[j]-m0); sc1[j]=__expf(sc1[j]-m1); s0+=sc0[j]; s1+=sc1[j]; }
  s0 = wave_sum(s0); s1 = wave_sum(s1);
  const float i0=1.0f/s0, i1=1.0f/s1;
  #pragma unroll
  for(int j=0;j<16;j++){ sc0[j]*=i0; sc1[j]*=i1; }

  // ---- pass 2: AV ----
  float acc0[16], acc1[16];
  #pragma unroll
  for(int dd=0;dd<16;dd++){ acc0[dd]=0.f; acc1[dd]=0.f; }
  #pragma unroll
  for(int ch=0;ch<4;ch++){
    __syncthreads();
    #pragma unroll
    for(int i=0;i<4;i++){
      const int f = tid + i*256, dd = f>>6, g = f&63;
      s_t[f] = ((const float4*)(vb + dd*1024 + ch*256))[g];
    }
    __syncthreads();
    #pragma unroll
    for(int dd=0;dd<16;dd++){
      const float4 vf = s_t[dd*64 + lane];
      acc0[dd]=fmaf(sc0[ch*4+0],vf.x,acc0[dd]); acc0[dd]=fmaf(sc0[ch*4+1],vf.y,acc0[dd]);
      acc0[dd]=fmaf(sc0[ch*4+2],vf.z,acc0[dd]); acc0[dd]=fmaf(sc0[ch*4+3],vf.w,acc0[dd]);
      acc1[dd]=fmaf(sc1[ch*4+0],vf.x,acc1[dd]); acc1[dd]=fmaf(sc1[ch*4+1],vf.y,acc1[dd]);
      acc1[dd]=fmaf(sc1[ch*4+2],vf.z,acc1[dd]); acc1[dd]=fmaf(sc1[ch*4+3],vf.w,acc1[dd]);
    }
  }
  #pragma unroll
  for(int dd=0;dd<16;dd++){ acc0[dd]=wave_sum(acc0[dd]); acc1[dd]=wave_sum(acc1[dd]); }
  {
    float val = 0.f;
    #pragma unroll
    for(int dd=0;dd<16;dd++){
      val = (lane==dd)    ? acc0[dd] : val;
      val = (lane==16+dd) ? acc1[dd] : val;
    }
    if (lane < 32) msg0[(size_t)(gq0 + (lane>>4))*16 + (lane&15)] = val;
  }
}

// ---------------- mid: K=64 gathered children, 4 queries/group, top-8 -------
template<bool TOK, bool TOKQ>
__global__ __launch_bounds__(256) void k_mid(
    const float* __restrict__ q, const float* __restrict__ k, const float* __restrict__ v,
    const float* __restrict__ ktok, const float* __restrict__ vtok,
    const float* __restrict__ qtok,
    const int* __restrict__ topk0, float* __restrict__ msg1, int* __restrict__ topk1)
{
  __shared__ float s_v[4][16][66];
  __shared__ float s_e[4][4][65];
  __shared__ float s_k[TOK?1:4][16][66];
  const int tid = threadIdx.x, wid = tid>>6, lane = tid&63;
  const int slot = __builtin_amdgcn_readfirstlane(blockIdx.x*4 + wid);
  const int l = slot & 1023, bh = slot >> 10;
  const int gy = l>>5, gx = l&31;
  const float* qb = q + (size_t)bh*65536;

  float kv[16];
  if constexpr (TOK){
    const int w = lane>>2, c = lane&3;
    const int widx = topk0[(size_t)slot*16 + w];
    const int pos = (2*(widx>>5) + (c>>1))*64 + 2*(widx&31) + (c&1);
    const float4* kp = (const float4*)(ktok + ((size_t)bh*4096 + pos)*16);
    float4 x0=kp[0], x1=kp[1], x2=kp[2], x3=kp[3];
    kv[0]=x0.x; kv[1]=x0.y; kv[2]=x0.z; kv[3]=x0.w;
    kv[4]=x1.x; kv[5]=x1.y; kv[6]=x1.z; kv[7]=x1.w;
    kv[8]=x2.x; kv[9]=x2.y; kv[10]=x2.z; kv[11]=x2.w;
    kv[12]=x3.x; kv[13]=x3.y; kv[14]=x3.z; kv[15]=x3.w;
    const float4* vp = (const float4*)(vtok + ((size_t)bh*4096 + pos)*16);
    float4 y0=vp[0], y1=vp[1], y2=vp[2], y3=vp[3];
    s_v[wid][0][lane]=y0.x;  s_v[wid][1][lane]=y0.y;  s_v[wid][2][lane]=y0.z;  s_v[wid][3][lane]=y0.w;
    s_v[wid][4][lane]=y1.x;  s_v[wid][5][lane]=y1.y;  s_v[wid][6][lane]=y1.z;  s_v[wid][7][lane]=y1.w;
    s_v[wid][8][lane]=y2.x;  s_v[wid][9][lane]=y2.y;  s_v[wid][10][lane]=y2.z; s_v[wid][11][lane]=y2.w;
    s_v[wid][12][lane]=y3.x; s_v[wid][13][lane]=y3.y; s_v[wid][14][lane]=y3.z; s_v[wid][15][lane]=y3.w;
  } else {
    const int kvsel = lane>>5, rr = lane&31, w = rr>>1, cy = rr&1;
    const int widx = topk0[(size_t)slot*16 + w];
    const int base = (2*(widx>>5) + cy)*64 + 2*(widx&31);
    const float* src = (kvsel ? v : k) + (size_t)bh*65536;
    float* dst = kvsel ? &s_v[wid][0][0] : &s_k[wid][0][0];
    const int key0 = w*4 + cy*2;
    #pragma unroll
    for(int dd=0;dd<16;dd++){
      const float2 f2 = *(const float2*)(src + dd*4096 + base);
      *(float2*)(dst + dd*66 + key0) = f2;
    }
    #pragma unroll
    for(int dd=0;dd<16;dd++) kv[dd] = s_k[wid][dd][lane];
  }

  // ---- scores + softmax (lane = gathered key) ----
  #pragma unroll
  for(int t=0;t<4;t++){
    const int qp = (2*gy + (t>>1))*64 + 2*gx + (t&1);
    float a = 0.f;
    if constexpr (TOKQ){
      const float* qr = qtok + ((size_t)bh*4096 + qp)*16;   // wave-uniform row
      #pragma unroll
      for(int dd=0;dd<16;dd++) a = fmaf(qr[dd], kv[dd], a);
    } else {
      #pragma unroll
      for(int dd=0;dd<16;dd++) a = fmaf(qb[dd*4096 + qp], kv[dd], a);
    }
    a *= 0.25f;
    const float m = wave_max(a);
    const float e = __expf(a - m);
    const float s = wave_sum(e);
    s_e[wid][t][lane] = e / s;
  }

  // ---- top-8: group g (16 lanes) handles t=g; lane j owns keys j*4+e ----
  const int g = lane>>4, j = lane&15;
  {
    const int wj_ = topk0[(size_t)slot*16 + j];
    const int tyj = wj_>>5, txj = wj_&31;
    int posj[4];
    #pragma unroll
    for(int e=0;e<4;e++) posj[e] = (2*tyj + (e>>1))*64 + 2*txj + (e&1);
    float ev[4];
    #pragma unroll
    for(int e=0;e<4;e++) ev[e] = s_e[wid][g][j*4+e];
    int cap = 0;
    for(int r=0;r<8;r++){
      float lv = ev[0]; int le = 0;
      #pragma unroll
      for(int e=1;e<4;e++) if (ev[e] > lv){ lv=ev[e]; le=e; }
      float gv = lv; int gk = j*4 + le;
      #pragma unroll
      for(int o=8;o>0;o>>=1){
        float ov = __shfl_xor(gv,o,64); int ok = __shfl_xor(gk,o,64);
        if (ov > gv || (ov == gv && ok < gk)){ gv=ov; gk=ok; }
      }
      const int estar = gk&3, h = gk>>2;
      int seli = posj[0];
      seli = (estar==1) ? posj[1] : seli;
      seli = (estar==2) ? posj[2] : seli;
      seli = (estar==3) ? posj[3] : seli;
      const int wpos = __shfl(seli, (lane & 48) | h, 64);
      #pragma unroll
      for(int e=0;e<4;e++) if (j==h && e==estar) ev[e] = -1e30f;
      if (j == r) cap = wpos;
    }
    if (j < 8){
      const int sp = (2*gy + (g>>1))*64 + 2*gx + (g&1);
      topk1[((size_t)bh*4096 + sp)*8 + j] = cap;
    }
  }

  // ---- msg1 = A @ gathered V: lane = (t,dd) ----
  {
    const int t = lane>>4, dd = lane&15;
    float a = 0.f;
    #pragma unroll
    for(int kk=0;kk<64;kk++) a = fmaf(s_e[wid][t][kk], s_v[wid][dd][kk], a);
    const int sp = (2*gy + (t>>1))*64 + 2*gx + (t&1);
    msg1[((size_t)bh*4096 + sp)*16 + dd] = a;
  }
}

// ---------------- fine: K=32 gathered children + fused combine --------------
template<bool TOK, bool TOKQ>
__global__ __launch_bounds__(256) void k_fine(
    const float* __restrict__ q, const float* __restrict__ k, const float* __restrict__ v,
    const float* __restrict__ ktok, const float* __restrict__ vtok,
    const float* __restrict__ qtok,
    const int* __restrict__ topk1, const float* __restrict__ msg0,
    const float* __restrict__ msg1, const float* __restrict__ wvec,
    float* __restrict__ out)
{
  __shared__ float s_k[4][16][34];
  __shared__ float s_v[4][16][34];
  __shared__ float s_q[4][4][17];
  __shared__ float s_e[4][4][33];
  const int tid = threadIdx.x, wid = tid>>6, lane = tid&63;
  const int slot = __builtin_amdgcn_readfirstlane(blockIdx.x*4 + wid);
  const int l = slot & 4095, bh = slot >> 12;
  const int b = bh>>3, h = bh&7;
  const int gy = l>>6, gx = l&63;

  const float* qb = q + (size_t)bh*262144;

  if constexpr (TOKQ){
    if (lane < 16){
      const int t = lane>>2, f4 = lane&3;
      const int qp = (2*gy + (t>>1))*128 + 2*gx + (t&1);
      const float4 x = ((const float4*)(qtok + ((size_t)bh*16384 + qp)*16))[f4];
      s_q[wid][t][f4*4+0]=x.x; s_q[wid][t][f4*4+1]=x.y;
      s_q[wid][t][f4*4+2]=x.z; s_q[wid][t][f4*4+3]=x.w;
    }
  } else {
    const int t = lane>>4, dd = lane&15;
    const int qp = (2*gy + (t>>1))*128 + 2*gx + (t&1);
    s_q[wid][t][dd] = qb[dd*16384 + qp];
  }
  if constexpr (TOK){
    const int key = lane&31, half = lane>>5;
    const int w = key>>2, c = key&3;
    const int widx = topk1[(size_t)slot*8 + w];
    const int pos = (2*(widx>>6) + (c>>1))*128 + 2*(widx&63) + (c&1);
    const float4* sp4 = (const float4*)((half ? vtok : ktok) + ((size_t)bh*16384 + pos)*16);
    float4 x0=sp4[0], x1=sp4[1], x2=sp4[2], x3=sp4[3];
    float* dst = (half ? &s_v[wid][0][0] : &s_k[wid][0][0]);
    dst[0*34+key]=x0.x;  dst[1*34+key]=x0.y;  dst[2*34+key]=x0.z;  dst[3*34+key]=x0.w;
    dst[4*34+key]=x1.x;  dst[5*34+key]=x1.y;  dst[6*34+key]=x1.z;  dst[7*34+key]=x1.w;
    dst[8*34+key]=x2.x;  dst[9*34+key]=x2.y;  dst[10*34+key]=x2.z; dst[11*34+key]=x2.w;
    dst[12*34+key]=x3.x; dst[13*34+key]=x3.y; dst[14*34+key]=x3.z; dst[15*34+key]=x3.w;
  } else {
    const int gs = lane>>1, dh = lane&1;
    const int kvsel = gs>>4, rr = gs&15, w = rr>>1, cy = rr&1;
    const int widx = topk1[(size_t)slot*8 + w];
    const int base = (2*(widx>>6) + cy)*128 + 2*(widx&63);
    const float* src = (kvsel ? v : k) + (size_t)bh*262144;
    float* dst = kvsel ? &s_v[wid][0][0] : &s_k[wid][0][0];
    const int key0 = w*4 + cy*2;
    #pragma unroll
    for(int jj=0;jj<8;jj++){
      const int dd = dh*8 + jj;
      const float2 f2 = *(const float2*)(src + dd*16384 + base);
      *(float2*)(dst + dd*34 + key0) = f2;
    }
  }

  const int key = lane&31, th = lane>>5;
  float kv[16];
  #pragma unroll
  for(int dd=0;dd<16;dd++) kv[dd] = s_k[wid][dd][key];
  #pragma unroll
  for(int tt=0;tt<2;tt++){
    const int t = th*2 + tt;
    float a = 0.f;
    #pragma unroll
    for(int dd=0;dd<16;dd++) a = fmaf(s_q[wid][t][dd], kv[dd], a);
    a *= 0.25f;
    const float m = half_max(a);
    const float e = __expf(a - m);
    const float s = half_sum(e);
    s_e[wid][t][key] = e / s;
  }

  const float w0i = wvec[0], w1i = wvec[1], w2i = wvec[2];
  const float wm = fmaxf(w0i, fmaxf(w1i, w2i));
  float e0 = __expf(w0i-wm), e1 = __expf(w1i-wm), e2 = __expf(w2i-wm);
  const float wsum = e0+e1+e2;
  e0/=wsum; e1/=wsum; e2/=wsum;

  const int t2 = lane>>4, dd2 = lane&15;
  float a = 0.f;
  #pragma unroll
  for(int kk=0;kk<32;kk++) a = fmaf(s_e[wid][t2][kk], s_v[wid][dd2][kk], a);

  const int cl = (gy>>1)*32 + (gx>>1);
  const float m0 = msg0[((size_t)bh*1024 + cl)*16 + dd2];
  const float m1 = msg1[(size_t)slot*16 + dd2];
  const int pp = (2*gy + (t2>>1))*128 + 2*gx + (t2&1);
  out[(((size_t)b*16384 + pp)*8 + h)*16 + dd2] = e0*m0 + e1*m1 + e2*a;
}

extern "C" void kernel_launch(void* const* d_in, const int* in_sizes, int n_in,
                              void* d_out, int out_size, void* d_ws, size_t ws_size,
                              hipStream_t stream) {
  const float* q0 = (const float*)d_in[0];
  const float* q1 = (const float*)d_in[1];
  const float* q2 = (const float*)d_in[2];
  const float* k0 = (const float*)d_in[3];
  const float* k1 = (const float*)d_in[4];
  const float* k2 = (const float*)d_in[5];
  const float* v0 = (const float*)d_in[6];
  const float* v1 = (const float*)d_in[7];
  const float* v2 = (const float*)d_in[8];
  const float* wv = (const float*)d_in[9];
  float* out = (float*)d_out;

  float* msg0  = (float*)d_ws;                 // 524288 f
  int*   topk0 = (int*)(msg0 + 524288);        // 524288 i
  float* msg1  = (float*)(topk0 + 524288);     // 2097152 f
  int*   topk1 = (int*)(msg1 + 2097152);       // 1048576 i
  float* ktok0 = (float*)(topk1 + 1048576);    // 8388608 f
  float* vtok0 = ktok0 + 8388608;              // 8388608 f
  float* ktok1 = vtok0 + 8388608;              // 2097152 f
  float* vtok1 = ktok1 + 2097152;              // 2097152 f
  float* qtok0 = vtok1 + 2097152;              // 8388608 f
  float* qtok1 = qtok0 + 8388608;              // 2097152 f

  const size_t needC = (size_t)(4194304 + 31457280) * 4;  // 142,606,336 B
  const size_t needA = (size_t)(4194304 + 20971520) * 4;  // 100,663,296 B

  hipLaunchKernelGGL(k_coarse, dim3(4096), dim3(256), 0, stream, q2, k2, v2, msg0, topk0);

  if (ws_size >= needC){
    hipLaunchKernelGGL(k_transpose_all<true>, dim3(7680), dim3(256), 0, stream,
                       k0,v0,q0,k1,v1,q1, ktok0,vtok0,qtok0,ktok1,vtok1,qtok1);
    hipLaunchKernelGGL((k_mid<true,true>),  dim3(8192),  dim3(256), 0, stream,
                       q1,k1,v1, ktok1,vtok1,qtok1, topk0, msg1, topk1);
    hipLaunchKernelGGL((k_fine<true,true>), dim3(32768), dim3(256), 0, stream,
                       q0,k0,v0, ktok0,vtok0,qtok0, topk1, msg0, msg1, wv, out);
  } else if (ws_size >= needA){
    hipLaunchKernelGGL(k_transpose_all<false>, dim3(5120), dim3(256), 0, stream,
                       k0,v0,q0,k1,v1,q1, ktok0,vtok0,qtok0,ktok1,vtok1,qtok1);
    hipLaunchKernelGGL((k_mid<true,false>),  dim3(8192),  dim3(256), 0, stream,
                       q1,k1,v1, ktok1,vtok1,qtok1, topk0, msg1, topk1);
    hipLaunchKernelGGL((k_fine<true,false>), dim3(32768), dim3(256), 0, stream,
                       q0,k0,v0, ktok0,vtok0,qtok0, topk1, msg0, msg1, wv, out);
  } else {
    hipLaunchKernelGGL((k_mid<false,false>),  dim3(8192),  dim3(256), 0, stream,
                       q1,k1,v1, (float*)d_ws,(float*)d_ws,(float*)d_ws, topk0, msg1, topk1);
    hipLaunchKernelGGL((k_fine<false,false>), dim3(32768), dim3(256), 0, stream,
                       q0,k0,v0, (float*)d_ws,(float*)d_ws,(float*)d_ws, topk1, msg0, msg1, wv, out);
  }
}